// Round 6
// baseline (439.685 us; speedup 1.0000x reference)
//
#include <hip/hip_runtime.h>
#include <cstdint>
#include <cstddef>

#define B_    4
#define L_    1024
#define DIM_  256
#define DI_   512
#define NTOK  (B_*L_)
#define CL    256          // scan chunk length
#define NC    4            // number of chunks

__device__ __forceinline__ float siluf_(float x){ return x / (1.0f + __expf(-x)); }
__device__ __forceinline__ float softplusf_(float x){
  return (x > 15.0f) ? x : log1pf(__expf(x));
}

// ---------- LN stats: one wave per token ----------
__global__ __launch_bounds__(256) void k_ln_stats(const float* __restrict__ x,
    float* __restrict__ stats){
  int tok  = blockIdx.x * 4 + (threadIdx.x >> 6);
  int lane = threadIdx.x & 63;
  float4 v = *(const float4*)(x + (size_t)tok * DIM_ + lane * 4);
  float s  = v.x + v.y + v.z + v.w;
  float sq = v.x*v.x + v.y*v.y + v.z*v.z + v.w*v.w;
  #pragma unroll
  for (int off = 32; off; off >>= 1){
    s  += __shfl_xor(s,  off, 64);
    sq += __shfl_xor(sq, off, 64);
  }
  if (lane == 0){
    float mu = s * (1.0f / DIM_);
    stats[tok*2]   = mu;
    stats[tok*2+1] = rsqrtf(sq * (1.0f / DIM_) - mu*mu + 1e-5f);
  }
}

// ---------- GEMM1 (LN fused): xz[m,n] = LN(x)[m,:] . W_in[n,:]  (4096x1024x256) ----------
__global__ __launch_bounds__(256) void k_gemm1(const float* __restrict__ x,
    const float* __restrict__ stats, const float* __restrict__ gamma,
    const float* __restrict__ beta, const float* __restrict__ Win,
    float* __restrict__ xz){
  __shared__ float As[16][64];
  __shared__ float Bs[16][64];
  int tid = threadIdx.x;
  int mBase = blockIdx.y * 64;
  int nBase = blockIdx.x * 64;
  int tx = tid & 15, ty = tid >> 4;
  int am = tid >> 2, ak = (tid & 3) << 2;
  float mu = stats[(mBase+am)*2], rs = stats[(mBase+am)*2+1];
  float acc[4][4] = {};
  for (int kt = 0; kt < 256; kt += 16){
    float4 av = *(const float4*)(x   + (size_t)(mBase+am)*256 + kt + ak);
    float4 bv = *(const float4*)(Win + (size_t)(nBase+am)*256 + kt + ak);
    float4 gv = *(const float4*)(gamma + kt + ak);
    float4 be = *(const float4*)(beta  + kt + ak);
    As[ak+0][am] = (av.x - mu) * rs * gv.x + be.x;
    As[ak+1][am] = (av.y - mu) * rs * gv.y + be.y;
    As[ak+2][am] = (av.z - mu) * rs * gv.z + be.z;
    As[ak+3][am] = (av.w - mu) * rs * gv.w + be.w;
    Bs[ak+0][am]=bv.x; Bs[ak+1][am]=bv.y; Bs[ak+2][am]=bv.z; Bs[ak+3][am]=bv.w;
    __syncthreads();
    #pragma unroll
    for (int kk = 0; kk < 16; kk++){
      float a[4], b[4];
      #pragma unroll
      for (int i=0;i<4;i++) a[i] = As[kk][ty*4+i];
      #pragma unroll
      for (int j=0;j<4;j++) b[j] = Bs[kk][tx*4+j];
      #pragma unroll
      for (int i=0;i<4;i++)
        #pragma unroll
        for (int j=0;j<4;j++)
          acc[i][j] += a[i]*b[j];
    }
    __syncthreads();
  }
  #pragma unroll
  for (int i=0;i<4;i++){
    float4 o = make_float4(acc[i][0],acc[i][1],acc[i][2],acc[i][3]);
    *(float4*)(xz + (size_t)(mBase+ty*4+i)*1024 + nBase + tx*4) = o;
  }
}

// ---------- causal depthwise conv (w=4) + SiLU ----------
__global__ __launch_bounds__(256) void k_conv(const float* __restrict__ xz,
    const float* __restrict__ cw, const float* __restrict__ cb,
    float* __restrict__ uc){
  int g = blockIdx.x * 256 + threadIdx.x;
  int d = g & 511;
  int tok = g >> 9;
  int t = tok & (L_ - 1);
  float w0 = cw[d*4+0], w1 = cw[d*4+1], w2 = cw[d*4+2], w3 = cw[d*4+3];
  const float* up = xz + (size_t)tok * 1024 + d;
  float acc = cb[d] + w3 * up[0];
  if (t >= 1) acc += w2 * up[-1 * 1024];
  if (t >= 2) acc += w1 * up[-2 * 1024];
  if (t >= 3) acc += w0 * up[-3 * 1024];
  uc[g] = siluf_(acc);
}

// ---------- GEMM2 tiled: dbl[m,n] = uc[m,:] . W_x[n,:]  (4096x80x512) ----------
__global__ __launch_bounds__(256) void k_gemm2(const float* __restrict__ uc,
    const float* __restrict__ Wx, float* __restrict__ dbl){
  __shared__ float As[16][64];
  __shared__ float Bs[16][80];
  int tid = threadIdx.x;
  int mBase = blockIdx.x * 64;
  int tx = tid & 15, ty = tid >> 4;
  int am = tid >> 2, ak = (tid & 3) << 2;
  float acc[4][5] = {};
  for (int kt = 0; kt < 512; kt += 16){
    float4 av = *(const float4*)(uc + (size_t)(mBase+am)*512 + kt + ak);
    As[ak+0][am]=av.x; As[ak+1][am]=av.y; As[ak+2][am]=av.z; As[ak+3][am]=av.w;
    for (int idx = tid; idx < 80*16; idx += 256){
      int bn = idx >> 4, bk = idx & 15;
      Bs[bk][bn] = Wx[(size_t)bn*512 + kt + bk];
    }
    __syncthreads();
    #pragma unroll
    for (int kk=0;kk<16;kk++){
      float a[4], b[5];
      #pragma unroll
      for (int i=0;i<4;i++) a[i] = As[kk][ty*4+i];
      #pragma unroll
      for (int j=0;j<5;j++) b[j] = Bs[kk][tx*5+j];
      #pragma unroll
      for (int i=0;i<4;i++)
        #pragma unroll
        for (int j=0;j<5;j++)
          acc[i][j] += a[i]*b[j];
    }
    __syncthreads();
  }
  #pragma unroll
  for (int i=0;i<4;i++)
    #pragma unroll
    for (int j=0;j<5;j++)
      dbl[(size_t)(mBase+ty*4+i)*80 + tx*5 + j] = acc[i][j];
}

// ---------- dt[m,d] = softplus(dbl[m,:16] . W_dt[d,:] + b_dt[d]) ----------
__global__ __launch_bounds__(256) void k_dt(const float* __restrict__ dbl,
    const float* __restrict__ Wdt, const float* __restrict__ bdt,
    float* __restrict__ dt){
  int g = blockIdx.x * 256 + threadIdx.x;
  int d = g & 511; int m = g >> 9;
  float acc = bdt[d];
  const float* r = dbl + (size_t)m * 80;
  #pragma unroll
  for (int k = 0; k < 16; k++)
    acc += r[k] * Wdt[d * 16 + k];
  dt[g] = softplusf_(acc);
}

// ---------- scan pass A: chunk-local h (no y) + sum(dt); 8192 waves ----------
__global__ __launch_bounds__(256) void k_scanA(const float* __restrict__ dt,
    const float* __restrict__ uc, const float* __restrict__ dbl,
    const float* __restrict__ A_log,
    float* __restrict__ hseg, float* __restrict__ S){
  int w    = (blockIdx.x * 256 + threadIdx.x) >> 6;  // 0..8191
  int lane = threadIdx.x & 63;
  int ch = w & 2047;          // (b,d)
  int c  = w >> 11;           // chunk 0..3
  int b = ch >> 9, d = ch & 511;
  float A = -__expf(A_log[(size_t)d * 64 + lane]);
  const float* dtp = dt  + (size_t)b * L_ * 512 + d;
  const float* ucp = uc  + (size_t)b * L_ * 512 + d;
  const float* Bp  = dbl + (size_t)b * L_ * 80  + 16 + lane;
  float h = 0.f, Ssum = 0.f;
  int tbeg = c * CL;
  for (int t0 = tbeg; t0 < tbeg + CL; t0 += 8){
    float dtv[8], uv[8], Bv[8];
    #pragma unroll
    for (int j = 0; j < 8; j++){
      dtv[j] = dtp[(size_t)(t0+j) * 512];
      uv[j]  = ucp[(size_t)(t0+j) * 512];
      Bv[j]  = Bp [(size_t)(t0+j) * 80];
    }
    #pragma unroll
    for (int j = 0; j < 8; j++){
      float dA = __expf(dtv[j] * A);
      h = dA * h + (dtv[j] * uv[j]) * Bv[j];
      Ssum += dtv[j];
    }
  }
  hseg[((size_t)(c * 2048 + ch)) * 64 + lane] = h;
  if (lane == 0) S[c * 2048 + ch] = Ssum;
}

// ---------- scan pass B: sequential chunk combine -> h_in per chunk; 2048 waves ----------
__global__ __launch_bounds__(256) void k_scanB(const float* __restrict__ hseg,
    const float* __restrict__ S, const float* __restrict__ A_log,
    float* __restrict__ hin){
  int ch   = (blockIdx.x * 256 + threadIdx.x) >> 6;  // 0..2047
  int lane = threadIdx.x & 63;
  int d = ch & 511;
  float A = -__expf(A_log[(size_t)d * 64 + lane]);
  float hc = 0.f;
  #pragma unroll
  for (int c = 0; c < NC; c++){
    size_t idx = ((size_t)(c * 2048 + ch)) * 64 + lane;
    hin[idx] = hc;
    float hf = hseg[idx];
    float Sv = S[c * 2048 + ch];
    hc = hf + __expf(A * Sv) * hc;
  }
}

// ---------- scan pass C: rescan chunk from h_in, y-butterfly, fused gate; 8192 waves ----------
__global__ __launch_bounds__(256) void k_scanC(const float* __restrict__ dt,
    const float* __restrict__ uc, const float* __restrict__ dbl,
    const float* __restrict__ C_SA, const float* __restrict__ A_log,
    const float* __restrict__ hin, const float* __restrict__ xz,
    const float* __restrict__ Dp, float* __restrict__ gate){
  int w    = (blockIdx.x * 256 + threadIdx.x) >> 6;  // 0..8191
  int lane = threadIdx.x & 63;
  int ch = w & 2047;
  int c  = w >> 11;
  int b = ch >> 9, d = ch & 511;
  float A  = -__expf(A_log[(size_t)d * 64 + lane]);
  float Dd = Dp[d];
  const float* dtp = dt   + (size_t)b * L_ * 512 + d;
  const float* ucp = uc   + (size_t)b * L_ * 512 + d;
  const float* Bp  = dbl  + (size_t)b * L_ * 80  + 16 + lane;
  const float* Cp  = C_SA + (size_t)b * L_ * 64  + lane;
  const float* zp  = xz   + (size_t)b * L_ * 1024 + 512 + d;
  float*       gp  = gate + (size_t)b * L_ * 512 + d;
  float h = hin[((size_t)(c * 2048 + ch)) * 64 + lane];
  int tbeg = c * CL;
  for (int t0 = tbeg; t0 < tbeg + CL; t0 += 8){
    float dtv[8], uv[8], Bv[8], Cv[8], zv[8];
    #pragma unroll
    for (int j = 0; j < 8; j++){
      dtv[j] = dtp[(size_t)(t0+j) * 512];
      uv[j]  = ucp[(size_t)(t0+j) * 512];
      Bv[j]  = Bp [(size_t)(t0+j) * 80];
      Cv[j]  = Cp [(size_t)(t0+j) * 64];
      zv[j]  = zp [(size_t)(t0+j) * 1024];
    }
    float yp[8];
    #pragma unroll
    for (int j = 0; j < 8; j++){
      float dA = __expf(dtv[j] * A);
      h = dA * h + (dtv[j] * uv[j]) * Bv[j];
      yp[j] = h * Cv[j];
    }
    #pragma unroll
    for (int off = 32; off; off >>= 1){
      #pragma unroll
      for (int j = 0; j < 8; j++)
        yp[j] += __shfl_xor(yp[j], off, 64);
    }
    if (lane == 0){
      #pragma unroll
      for (int j = 0; j < 8; j++)
        gp[(size_t)(t0+j) * 512] = (yp[j] + uv[j] * Dd) * siluf_(zv[j]);
    }
  }
}

// ---------- GEMM3 tiled: out[m,n] = gate[m,:] . W_out[n,:]  (4096x256x512) ----------
__global__ __launch_bounds__(256) void k_gemm3(const float* __restrict__ gate,
    const float* __restrict__ Wout, float* __restrict__ out){
  __shared__ float As[16][64];
  __shared__ float Bs[16][64];
  int tid = threadIdx.x;
  int mBase = blockIdx.y * 64;
  int nBase = blockIdx.x * 64;
  int tx = tid & 15, ty = tid >> 4;
  int am = tid >> 2, ak = (tid & 3) << 2;
  float acc[4][4] = {};
  for (int kt = 0; kt < 512; kt += 16){
    float4 av = *(const float4*)(gate + (size_t)(mBase+am)*512 + kt + ak);
    float4 bv = *(const float4*)(Wout + (size_t)(nBase+am)*512 + kt + ak);
    As[ak+0][am]=av.x; As[ak+1][am]=av.y; As[ak+2][am]=av.z; As[ak+3][am]=av.w;
    Bs[ak+0][am]=bv.x; Bs[ak+1][am]=bv.y; Bs[ak+2][am]=bv.z; Bs[ak+3][am]=bv.w;
    __syncthreads();
    #pragma unroll
    for (int kk=0;kk<16;kk++){
      float a[4], b[4];
      #pragma unroll
      for (int i=0;i<4;i++) a[i] = As[kk][ty*4+i];
      #pragma unroll
      for (int j=0;j<4;j++) b[j] = Bs[kk][tx*4+j];
      #pragma unroll
      for (int i=0;i<4;i++)
        #pragma unroll
        for (int j=0;j<4;j++)
          acc[i][j] += a[i]*b[j];
    }
    __syncthreads();
  }
  #pragma unroll
  for (int i=0;i<4;i++){
    float4 o = make_float4(acc[i][0],acc[i][1],acc[i][2],acc[i][3]);
    *(float4*)(out + (size_t)(mBase+ty*4+i)*256 + nBase + tx*4) = o;
  }
}

extern "C" void kernel_launch(void* const* d_in, const int* in_sizes, int n_in,
                              void* d_out, int out_size, void* d_ws, size_t ws_size,
                              hipStream_t stream) {
  const float* x      = (const float*)d_in[0];
  const float* C_SA   = (const float*)d_in[1];
  const float* gamma  = (const float*)d_in[2];
  const float* beta   = (const float*)d_in[3];
  const float* W_in   = (const float*)d_in[4];
  const float* conv_w = (const float*)d_in[5];
  const float* conv_b = (const float*)d_in[6];
  const float* W_x    = (const float*)d_in[7];
  const float* W_dt   = (const float*)d_in[8];
  const float* b_dt   = (const float*)d_in[9];
  const float* A_log  = (const float*)d_in[10];
  const float* Dw     = (const float*)d_in[11];
  const float* W_out  = (const float*)d_in[12];
  float* out = (float*)d_out;

  float* ws    = (float*)d_ws;
  float* stats = ws;                        // 8192 used (1M-slot reserved)
  float* xz    = ws   + 1048576;            // 4096*1024
  float* uc    = xz   + 4194304;            // 4096*512
  float* dbl   = uc   + 2097152;            // 4096*80
  float* dtb   = dbl  + 327680;             // 4096*512
  float* scanb = dtb  + 2097152;            // scan state (in old ys slot)
  float* hseg  = scanb;                     // 4*2048*64 = 524288
  float* hin   = scanb + 524288;            // 524288
  float* S     = scanb + 1048576;           // 8192
  float* gate  = scanb + 2097152;           // 4096*512

  k_ln_stats<<<NTOK/4, 256, 0, stream>>>(x, stats);
  k_gemm1<<<dim3(16, 64), 256, 0, stream>>>(x, stats, gamma, beta, W_in, xz);
  k_conv <<<(NTOK*512)/256, 256, 0, stream>>>(xz, conv_w, conv_b, uc);
  k_gemm2<<<64, 256, 0, stream>>>(uc, W_x, dbl);
  k_dt   <<<(NTOK*512)/256, 256, 0, stream>>>(dbl, W_dt, b_dt, dtb);
  k_scanA<<<2048, 256, 0, stream>>>(dtb, uc, dbl, A_log, hseg, S);
  k_scanB<<<512, 256, 0, stream>>>(hseg, S, A_log, hin);
  k_scanC<<<2048, 256, 0, stream>>>(dtb, uc, dbl, C_SA, A_log, hin, xz, Dw, gate);
  k_gemm3<<<dim3(4, 64), 256, 0, stream>>>(gate, W_out, out);
}

// Round 7
// 357.892 us; speedup vs baseline: 1.2285x; 1.2285x over previous
//
#include <hip/hip_runtime.h>
#include <cstdint>
#include <cstddef>

#define B_    4
#define L_    1024
#define DIM_  256
#define DI_   512
#define NTOK  (B_*L_)
#define NC    8            // scan chunks
#define CL    (L_/NC)      // chunk length = 128

__device__ __forceinline__ float siluf_(float x){ return x / (1.0f + __expf(-x)); }
__device__ __forceinline__ float softplusf_(float x){
  return (x > 15.0f) ? x : log1pf(__expf(x));
}

// ---------- LN stats: one wave per token ----------
__global__ __launch_bounds__(256) void k_ln_stats(const float* __restrict__ x,
    float* __restrict__ stats){
  int tok  = blockIdx.x * 4 + (threadIdx.x >> 6);
  int lane = threadIdx.x & 63;
  float4 v = *(const float4*)(x + (size_t)tok * DIM_ + lane * 4);
  float s  = v.x + v.y + v.z + v.w;
  float sq = v.x*v.x + v.y*v.y + v.z*v.z + v.w*v.w;
  #pragma unroll
  for (int off = 32; off; off >>= 1){
    s  += __shfl_xor(s,  off, 64);
    sq += __shfl_xor(sq, off, 64);
  }
  if (lane == 0){
    float mu = s * (1.0f / DIM_);
    stats[tok*2]   = mu;
    stats[tok*2+1] = rsqrtf(sq * (1.0f / DIM_) - mu*mu + 1e-5f);
  }
}

// ---------- GEMM1 (LN fused): xz[m,n] = LN(x)[m,:] . W_in[n,:]  (4096x1024x256) ----------
__global__ __launch_bounds__(256) void k_gemm1(const float* __restrict__ x,
    const float* __restrict__ stats, const float* __restrict__ gamma,
    const float* __restrict__ beta, const float* __restrict__ Win,
    float* __restrict__ xz){
  __shared__ float As[16][64];
  __shared__ float Bs[16][64];
  int tid = threadIdx.x;
  int mBase = blockIdx.y * 64;
  int nBase = blockIdx.x * 64;
  int tx = tid & 15, ty = tid >> 4;
  int am = tid >> 2, ak = (tid & 3) << 2;
  float mu = stats[(mBase+am)*2], rs = stats[(mBase+am)*2+1];
  float acc[4][4] = {};
  for (int kt = 0; kt < 256; kt += 16){
    float4 av = *(const float4*)(x   + (size_t)(mBase+am)*256 + kt + ak);
    float4 bv = *(const float4*)(Win + (size_t)(nBase+am)*256 + kt + ak);
    float4 gv = *(const float4*)(gamma + kt + ak);
    float4 be = *(const float4*)(beta  + kt + ak);
    As[ak+0][am] = (av.x - mu) * rs * gv.x + be.x;
    As[ak+1][am] = (av.y - mu) * rs * gv.y + be.y;
    As[ak+2][am] = (av.z - mu) * rs * gv.z + be.z;
    As[ak+3][am] = (av.w - mu) * rs * gv.w + be.w;
    Bs[ak+0][am]=bv.x; Bs[ak+1][am]=bv.y; Bs[ak+2][am]=bv.z; Bs[ak+3][am]=bv.w;
    __syncthreads();
    #pragma unroll
    for (int kk = 0; kk < 16; kk++){
      float a[4], b[4];
      #pragma unroll
      for (int i=0;i<4;i++) a[i] = As[kk][ty*4+i];
      #pragma unroll
      for (int j=0;j<4;j++) b[j] = Bs[kk][tx*4+j];
      #pragma unroll
      for (int i=0;i<4;i++)
        #pragma unroll
        for (int j=0;j<4;j++)
          acc[i][j] += a[i]*b[j];
    }
    __syncthreads();
  }
  #pragma unroll
  for (int i=0;i<4;i++){
    float4 o = make_float4(acc[i][0],acc[i][1],acc[i][2],acc[i][3]);
    *(float4*)(xz + (size_t)(mBase+ty*4+i)*1024 + nBase + tx*4) = o;
  }
}

// ---------- causal depthwise conv (w=4) + SiLU ----------
__global__ __launch_bounds__(256) void k_conv(const float* __restrict__ xz,
    const float* __restrict__ cw, const float* __restrict__ cb,
    float* __restrict__ uc){
  int g = blockIdx.x * 256 + threadIdx.x;
  int d = g & 511;
  int tok = g >> 9;
  int t = tok & (L_ - 1);
  float w0 = cw[d*4+0], w1 = cw[d*4+1], w2 = cw[d*4+2], w3 = cw[d*4+3];
  const float* up = xz + (size_t)tok * 1024 + d;
  float acc = cb[d] + w3 * up[0];
  if (t >= 1) acc += w2 * up[-1 * 1024];
  if (t >= 2) acc += w1 * up[-2 * 1024];
  if (t >= 3) acc += w0 * up[-3 * 1024];
  uc[g] = siluf_(acc);
}

// ---------- GEMM2 tiled: dbl[m,n] = uc[m,:] . W_x[n,:]  (4096x80x512) ----------
__global__ __launch_bounds__(256) void k_gemm2(const float* __restrict__ uc,
    const float* __restrict__ Wx, float* __restrict__ dbl){
  __shared__ float As[16][64];
  __shared__ float Bs[16][80];
  int tid = threadIdx.x;
  int mBase = blockIdx.x * 64;
  int tx = tid & 15, ty = tid >> 4;
  int am = tid >> 2, ak = (tid & 3) << 2;
  float acc[4][5] = {};
  for (int kt = 0; kt < 512; kt += 16){
    float4 av = *(const float4*)(uc + (size_t)(mBase+am)*512 + kt + ak);
    As[ak+0][am]=av.x; As[ak+1][am]=av.y; As[ak+2][am]=av.z; As[ak+3][am]=av.w;
    for (int idx = tid; idx < 80*16; idx += 256){
      int bn = idx >> 4, bk = idx & 15;
      Bs[bk][bn] = Wx[(size_t)bn*512 + kt + bk];
    }
    __syncthreads();
    #pragma unroll
    for (int kk=0;kk<16;kk++){
      float a[4], b[5];
      #pragma unroll
      for (int i=0;i<4;i++) a[i] = As[kk][ty*4+i];
      #pragma unroll
      for (int j=0;j<5;j++) b[j] = Bs[kk][tx*5+j];
      #pragma unroll
      for (int i=0;i<4;i++)
        #pragma unroll
        for (int j=0;j<5;j++)
          acc[i][j] += a[i]*b[j];
    }
    __syncthreads();
  }
  #pragma unroll
  for (int i=0;i<4;i++)
    #pragma unroll
    for (int j=0;j<5;j++)
      dbl[(size_t)(mBase+ty*4+i)*80 + tx*5 + j] = acc[i][j];
}

// ---------- dt[m,d] = softplus(dbl[m,:16] . W_dt[d,:] + b_dt[d]) ----------
__global__ __launch_bounds__(256) void k_dt(const float* __restrict__ dbl,
    const float* __restrict__ Wdt, const float* __restrict__ bdt,
    float* __restrict__ dt){
  int g = blockIdx.x * 256 + threadIdx.x;
  int d = g & 511; int m = g >> 9;
  float acc = bdt[d];
  const float* r = dbl + (size_t)m * 80;
  #pragma unroll
  for (int k = 0; k < 16; k++)
    acc += r[k] * Wdt[d * 16 + k];
  dt[g] = softplusf_(acc);
}

// ---------- scan pass A: chunk-local h; lane owns 8 states of 1 channel ----------
// wave = 8 channels x 8 state-groups; 2048 waves total
__global__ __launch_bounds__(256) void k_scanA(const float* __restrict__ dt,
    const float* __restrict__ uc, const float* __restrict__ dbl,
    const float* __restrict__ A_log,
    float* __restrict__ hseg, float* __restrict__ S){
  int gw   = (blockIdx.x * 256 + threadIdx.x) >> 6;  // 0..2047
  int lane = threadIdx.x & 63;
  int dsub = lane & 7, ngrp = lane >> 3;
  int grp = gw & 255;          // channel group (8 channels)
  int c   = gw >> 8;           // chunk 0..7
  int ch  = grp * 8 + dsub;    // 0..2047
  int b = ch >> 9, d = ch & 511;
  float Aa[8];
  {
    float4 a0 = *(const float4*)(A_log + (size_t)d*64 + ngrp*8);
    float4 a1 = *(const float4*)(A_log + (size_t)d*64 + ngrp*8 + 4);
    Aa[0]=-__expf(a0.x); Aa[1]=-__expf(a0.y); Aa[2]=-__expf(a0.z); Aa[3]=-__expf(a0.w);
    Aa[4]=-__expf(a1.x); Aa[5]=-__expf(a1.y); Aa[6]=-__expf(a1.z); Aa[7]=-__expf(a1.w);
  }
  const float* dtp = dt  + (size_t)b * L_ * 512 + d;
  const float* ucp = uc  + (size_t)b * L_ * 512 + d;
  const float* Bp  = dbl + (size_t)b * L_ * 80  + 16 + ngrp*8;
  float h[8] = {};
  float Ssum = 0.f;
  int tbeg = c * CL;
  for (int t0 = tbeg; t0 < tbeg + CL; t0 += 4){
    float dt4[4], u4[4], Bv[4][8];
    #pragma unroll
    for (int j = 0; j < 4; j++){
      dt4[j] = dtp[(size_t)(t0+j) * 512];
      u4[j]  = ucp[(size_t)(t0+j) * 512];
      *(float4*)&Bv[j][0] = *(const float4*)(Bp + (size_t)(t0+j)*80);
      *(float4*)&Bv[j][4] = *(const float4*)(Bp + (size_t)(t0+j)*80 + 4);
    }
    #pragma unroll
    for (int j = 0; j < 4; j++){
      float sc = dt4[j] * u4[j];
      Ssum += dt4[j];
      #pragma unroll
      for (int i = 0; i < 8; i++)
        h[i] = __expf(dt4[j] * Aa[i]) * h[i] + sc * Bv[j][i];
    }
  }
  float* hp = hseg + ((size_t)(c * 2048 + ch)) * 64 + ngrp*8;
  *(float4*)hp     = make_float4(h[0],h[1],h[2],h[3]);
  *(float4*)(hp+4) = make_float4(h[4],h[5],h[6],h[7]);
  if (ngrp == 0) S[c * 2048 + ch] = Ssum;
}

// ---------- scan pass B: sequential chunk combine -> h_in; wave per channel ----------
__global__ __launch_bounds__(256) void k_scanB(const float* __restrict__ hseg,
    const float* __restrict__ S, const float* __restrict__ A_log,
    float* __restrict__ hin){
  int ch   = (blockIdx.x * 256 + threadIdx.x) >> 6;  // 0..2047
  int lane = threadIdx.x & 63;
  int d = ch & 511;
  float A = -__expf(A_log[(size_t)d * 64 + lane]);
  float hc = 0.f;
  #pragma unroll
  for (int c = 0; c < NC; c++){
    size_t idx = ((size_t)(c * 2048 + ch)) * 64 + lane;
    hin[idx] = hc;
    float hf = hseg[idx];
    float Sv = S[c * 2048 + ch];
    hc = hf + __expf(A * Sv) * hc;
  }
}

// ---------- scan pass C: rescan from h_in; 3-stage butterfly for 8 channels ----------
__global__ __launch_bounds__(256) void k_scanC(const float* __restrict__ dt,
    const float* __restrict__ uc, const float* __restrict__ dbl,
    const float* __restrict__ C_SA, const float* __restrict__ A_log,
    const float* __restrict__ hin, float* __restrict__ ys){
  int gw   = (blockIdx.x * 256 + threadIdx.x) >> 6;  // 0..2047
  int lane = threadIdx.x & 63;
  int dsub = lane & 7, ngrp = lane >> 3;
  int grp = gw & 255;
  int c   = gw >> 8;
  int ch  = grp * 8 + dsub;
  int b = ch >> 9, d = ch & 511;
  float Aa[8];
  {
    float4 a0 = *(const float4*)(A_log + (size_t)d*64 + ngrp*8);
    float4 a1 = *(const float4*)(A_log + (size_t)d*64 + ngrp*8 + 4);
    Aa[0]=-__expf(a0.x); Aa[1]=-__expf(a0.y); Aa[2]=-__expf(a0.z); Aa[3]=-__expf(a0.w);
    Aa[4]=-__expf(a1.x); Aa[5]=-__expf(a1.y); Aa[6]=-__expf(a1.z); Aa[7]=-__expf(a1.w);
  }
  const float* dtp = dt   + (size_t)b * L_ * 512 + d;
  const float* ucp = uc   + (size_t)b * L_ * 512 + d;
  const float* Bp  = dbl  + (size_t)b * L_ * 80  + 16 + ngrp*8;
  const float* Cp  = C_SA + (size_t)b * L_ * 64  + ngrp*8;
  float*       yw  = ys   + (size_t)b * L_ * 512 + d;
  float h[8];
  {
    const float* hp = hin + ((size_t)(c * 2048 + ch)) * 64 + ngrp*8;
    float4 h0 = *(const float4*)hp;
    float4 h1 = *(const float4*)(hp + 4);
    h[0]=h0.x; h[1]=h0.y; h[2]=h0.z; h[3]=h0.w;
    h[4]=h1.x; h[5]=h1.y; h[6]=h1.z; h[7]=h1.w;
  }
  int tbeg = c * CL;
  for (int t0 = tbeg; t0 < tbeg + CL; t0 += 4){
    float dt4[4], u4[4], Bv[4][8], Cv[4][8];
    #pragma unroll
    for (int j = 0; j < 4; j++){
      dt4[j] = dtp[(size_t)(t0+j) * 512];
      u4[j]  = ucp[(size_t)(t0+j) * 512];
      *(float4*)&Bv[j][0] = *(const float4*)(Bp + (size_t)(t0+j)*80);
      *(float4*)&Bv[j][4] = *(const float4*)(Bp + (size_t)(t0+j)*80 + 4);
      *(float4*)&Cv[j][0] = *(const float4*)(Cp + (size_t)(t0+j)*64);
      *(float4*)&Cv[j][4] = *(const float4*)(Cp + (size_t)(t0+j)*64 + 4);
    }
    float yp[4];
    #pragma unroll
    for (int j = 0; j < 4; j++){
      float sc = dt4[j] * u4[j];
      float y = 0.f;
      #pragma unroll
      for (int i = 0; i < 8; i++){
        h[i] = __expf(dt4[j] * Aa[i]) * h[i] + sc * Bv[j][i];
        y += h[i] * Cv[j][i];
      }
      yp[j] = y;
    }
    // reduce over state-groups: lanes differing in bits 3..5
    #pragma unroll
    for (int off = 8; off < 64; off <<= 1){
      #pragma unroll
      for (int j = 0; j < 4; j++)
        yp[j] += __shfl_xor(yp[j], off, 64);
    }
    if (ngrp == 0){
      #pragma unroll
      for (int j = 0; j < 4; j++)
        yw[(size_t)(t0+j) * 512] = yp[j];
    }
  }
}

// ---------- GEMM3 (gate fused): out = ((ys+uc*D)*silu(z)) . W_out^T  (4096x256x512) ----------
__global__ __launch_bounds__(256) void k_gemm3(const float* __restrict__ ys,
    const float* __restrict__ uc, const float* __restrict__ xz,
    const float* __restrict__ Dp, const float* __restrict__ Wout,
    float* __restrict__ out){
  __shared__ float As[16][64];
  __shared__ float Bs[16][64];
  int tid = threadIdx.x;
  int mBase = blockIdx.y * 64;
  int nBase = blockIdx.x * 64;
  int tx = tid & 15, ty = tid >> 4;
  int am = tid >> 2, ak = (tid & 3) << 2;
  float acc[4][4] = {};
  for (int kt = 0; kt < 512; kt += 16){
    int m = mBase + am;
    float4 yv = *(const float4*)(ys + (size_t)m*512 + kt + ak);
    float4 uv = *(const float4*)(uc + (size_t)m*512 + kt + ak);
    float4 zv = *(const float4*)(xz + (size_t)m*1024 + 512 + kt + ak);
    float4 dv = *(const float4*)(Dp + kt + ak);
    float4 bv = *(const float4*)(Wout + (size_t)(nBase+am)*512 + kt + ak);
    As[ak+0][am] = (yv.x + uv.x*dv.x) * siluf_(zv.x);
    As[ak+1][am] = (yv.y + uv.y*dv.y) * siluf_(zv.y);
    As[ak+2][am] = (yv.z + uv.z*dv.z) * siluf_(zv.z);
    As[ak+3][am] = (yv.w + uv.w*dv.w) * siluf_(zv.w);
    Bs[ak+0][am]=bv.x; Bs[ak+1][am]=bv.y; Bs[ak+2][am]=bv.z; Bs[ak+3][am]=bv.w;
    __syncthreads();
    #pragma unroll
    for (int kk=0;kk<16;kk++){
      float a[4], b[4];
      #pragma unroll
      for (int i=0;i<4;i++) a[i] = As[kk][ty*4+i];
      #pragma unroll
      for (int j=0;j<4;j++) b[j] = Bs[kk][tx*4+j];
      #pragma unroll
      for (int i=0;i<4;i++)
        #pragma unroll
        for (int j=0;j<4;j++)
          acc[i][j] += a[i]*b[j];
    }
    __syncthreads();
  }
  #pragma unroll
  for (int i=0;i<4;i++){
    float4 o = make_float4(acc[i][0],acc[i][1],acc[i][2],acc[i][3]);
    *(float4*)(out + (size_t)(mBase+ty*4+i)*256 + nBase + tx*4) = o;
  }
}

extern "C" void kernel_launch(void* const* d_in, const int* in_sizes, int n_in,
                              void* d_out, int out_size, void* d_ws, size_t ws_size,
                              hipStream_t stream) {
  const float* x      = (const float*)d_in[0];
  const float* C_SA   = (const float*)d_in[1];
  const float* gamma  = (const float*)d_in[2];
  const float* beta   = (const float*)d_in[3];
  const float* W_in   = (const float*)d_in[4];
  const float* conv_w = (const float*)d_in[5];
  const float* conv_b = (const float*)d_in[6];
  const float* W_x    = (const float*)d_in[7];
  const float* W_dt   = (const float*)d_in[8];
  const float* b_dt   = (const float*)d_in[9];
  const float* A_log  = (const float*)d_in[10];
  const float* Dw     = (const float*)d_in[11];
  const float* W_out  = (const float*)d_in[12];
  float* out = (float*)d_out;

  float* ws    = (float*)d_ws;
  float* stats = ws;                        // 8192 used
  float* xz    = ws    + 1048576;           // 4096*1024
  float* uc    = xz    + 4194304;           // 4096*512
  float* dbl   = uc    + 2097152;           // 4096*80
  float* dtb   = dbl   + 327680;            // 4096*512
  float* hseg  = dtb   + 2097152;           // NC*2048*64 = 1048576
  float* hin   = hseg  + 1048576;           // 1048576
  float* S     = hin   + 1048576;           // NC*2048 = 16384
  float* ysb   = S     + 16384;             // 4096*512

  k_ln_stats<<<NTOK/4, 256, 0, stream>>>(x, stats);
  k_gemm1<<<dim3(16, 64), 256, 0, stream>>>(x, stats, gamma, beta, W_in, xz);
  k_conv <<<(NTOK*512)/256, 256, 0, stream>>>(xz, conv_w, conv_b, uc);
  k_gemm2<<<64, 256, 0, stream>>>(uc, W_x, dbl);
  k_dt   <<<(NTOK*512)/256, 256, 0, stream>>>(dbl, W_dt, b_dt, dtb);
  k_scanA<<<512, 256, 0, stream>>>(dtb, uc, dbl, A_log, hseg, S);
  k_scanB<<<512, 256, 0, stream>>>(hseg, S, A_log, hin);
  k_scanC<<<512, 256, 0, stream>>>(dtb, uc, dbl, C_SA, A_log, hin, ysb);
  k_gemm3<<<dim3(4, 64), 256, 0, stream>>>(ysb, uc, xz, Dw, W_out, out);
}

// Round 8
// 313.216 us; speedup vs baseline: 1.4038x; 1.1426x over previous
//
#include <hip/hip_runtime.h>
#include <cstdint>
#include <cstddef>

#define B_    4
#define L_    1024
#define DIM_  256
#define DI_   512
#define NTOK  (B_*L_)
#define NC    16           // scan chunks
#define CL    (L_/NC)      // chunk length = 64

__device__ __forceinline__ float siluf_(float x){ return x / (1.0f + __expf(-x)); }
__device__ __forceinline__ float softplusf_(float x){
  return (x > 15.0f) ? x : log1pf(__expf(x));
}

// ---------- LN stats: one wave per token ----------
__global__ __launch_bounds__(256) void k_ln_stats(const float* __restrict__ x,
    float* __restrict__ stats){
  int tok  = blockIdx.x * 4 + (threadIdx.x >> 6);
  int lane = threadIdx.x & 63;
  float4 v = *(const float4*)(x + (size_t)tok * DIM_ + lane * 4);
  float s  = v.x + v.y + v.z + v.w;
  float sq = v.x*v.x + v.y*v.y + v.z*v.z + v.w*v.w;
  #pragma unroll
  for (int off = 32; off; off >>= 1){
    s  += __shfl_xor(s,  off, 64);
    sq += __shfl_xor(sq, off, 64);
  }
  if (lane == 0){
    float mu = s * (1.0f / DIM_);
    stats[tok*2]   = mu;
    stats[tok*2+1] = rsqrtf(sq * (1.0f / DIM_) - mu*mu + 1e-5f);
  }
}

// ---------- GEMM1 (LN fused): xz[m,n] = LN(x)[m,:] . W_in[n,:]  (4096x1024x256) ----------
__global__ __launch_bounds__(256) void k_gemm1(const float* __restrict__ x,
    const float* __restrict__ stats, const float* __restrict__ gamma,
    const float* __restrict__ beta, const float* __restrict__ Win,
    float* __restrict__ xz){
  __shared__ float As[16][64];
  __shared__ float Bs[16][64];
  int tid = threadIdx.x;
  int mBase = blockIdx.y * 64;
  int nBase = blockIdx.x * 64;
  int tx = tid & 15, ty = tid >> 4;
  int am = tid >> 2, ak = (tid & 3) << 2;
  float mu = stats[(mBase+am)*2], rs = stats[(mBase+am)*2+1];
  float acc[4][4] = {};
  for (int kt = 0; kt < 256; kt += 16){
    float4 av = *(const float4*)(x   + (size_t)(mBase+am)*256 + kt + ak);
    float4 bv = *(const float4*)(Win + (size_t)(nBase+am)*256 + kt + ak);
    float4 gv = *(const float4*)(gamma + kt + ak);
    float4 be = *(const float4*)(beta  + kt + ak);
    As[ak+0][am] = (av.x - mu) * rs * gv.x + be.x;
    As[ak+1][am] = (av.y - mu) * rs * gv.y + be.y;
    As[ak+2][am] = (av.z - mu) * rs * gv.z + be.z;
    As[ak+3][am] = (av.w - mu) * rs * gv.w + be.w;
    Bs[ak+0][am]=bv.x; Bs[ak+1][am]=bv.y; Bs[ak+2][am]=bv.z; Bs[ak+3][am]=bv.w;
    __syncthreads();
    #pragma unroll
    for (int kk = 0; kk < 16; kk++){
      float a[4], b[4];
      #pragma unroll
      for (int i=0;i<4;i++) a[i] = As[kk][ty*4+i];
      #pragma unroll
      for (int j=0;j<4;j++) b[j] = Bs[kk][tx*4+j];
      #pragma unroll
      for (int i=0;i<4;i++)
        #pragma unroll
        for (int j=0;j<4;j++)
          acc[i][j] += a[i]*b[j];
    }
    __syncthreads();
  }
  #pragma unroll
  for (int i=0;i<4;i++){
    float4 o = make_float4(acc[i][0],acc[i][1],acc[i][2],acc[i][3]);
    *(float4*)(xz + (size_t)(mBase+ty*4+i)*1024 + nBase + tx*4) = o;
  }
}

// ---------- causal depthwise conv (w=4) + SiLU ----------
__global__ __launch_bounds__(256) void k_conv(const float* __restrict__ xz,
    const float* __restrict__ cw, const float* __restrict__ cb,
    float* __restrict__ uc){
  int g = blockIdx.x * 256 + threadIdx.x;
  int d = g & 511;
  int tok = g >> 9;
  int t = tok & (L_ - 1);
  float w0 = cw[d*4+0], w1 = cw[d*4+1], w2 = cw[d*4+2], w3 = cw[d*4+3];
  const float* up = xz + (size_t)tok * 1024 + d;
  float acc = cb[d] + w3 * up[0];
  if (t >= 1) acc += w2 * up[-1 * 1024];
  if (t >= 2) acc += w1 * up[-2 * 1024];
  if (t >= 3) acc += w0 * up[-3 * 1024];
  uc[g] = siluf_(acc);
}

// ---------- GEMM2 tiled: dbl[m,n] = uc[m,:] . W_x[n,:]  (4096x80x512) ----------
__global__ __launch_bounds__(256) void k_gemm2(const float* __restrict__ uc,
    const float* __restrict__ Wx, float* __restrict__ dbl){
  __shared__ float As[16][64];
  __shared__ float Bs[16][80];
  int tid = threadIdx.x;
  int mBase = blockIdx.x * 64;
  int tx = tid & 15, ty = tid >> 4;
  int am = tid >> 2, ak = (tid & 3) << 2;
  float acc[4][5] = {};
  for (int kt = 0; kt < 512; kt += 16){
    float4 av = *(const float4*)(uc + (size_t)(mBase+am)*512 + kt + ak);
    As[ak+0][am]=av.x; As[ak+1][am]=av.y; As[ak+2][am]=av.z; As[ak+3][am]=av.w;
    for (int idx = tid; idx < 80*16; idx += 256){
      int bn = idx >> 4, bk = idx & 15;
      Bs[bk][bn] = Wx[(size_t)bn*512 + kt + bk];
    }
    __syncthreads();
    #pragma unroll
    for (int kk=0;kk<16;kk++){
      float a[4], b[5];
      #pragma unroll
      for (int i=0;i<4;i++) a[i] = As[kk][ty*4+i];
      #pragma unroll
      for (int j=0;j<5;j++) b[j] = Bs[kk][tx*5+j];
      #pragma unroll
      for (int i=0;i<4;i++)
        #pragma unroll
        for (int j=0;j<5;j++)
          acc[i][j] += a[i]*b[j];
    }
    __syncthreads();
  }
  #pragma unroll
  for (int i=0;i<4;i++)
    #pragma unroll
    for (int j=0;j<5;j++)
      dbl[(size_t)(mBase+ty*4+i)*80 + tx*5 + j] = acc[i][j];
}

// ---------- dt[m,d] = softplus(dbl[m,:16] . W_dt[d,:] + b_dt[d]) ----------
__global__ __launch_bounds__(256) void k_dt(const float* __restrict__ dbl,
    const float* __restrict__ Wdt, const float* __restrict__ bdt,
    float* __restrict__ dt){
  int g = blockIdx.x * 256 + threadIdx.x;
  int d = g & 511; int m = g >> 9;
  float acc = bdt[d];
  const float* r = dbl + (size_t)m * 80;
  #pragma unroll
  for (int k = 0; k < 16; k++)
    acc += r[k] * Wdt[d * 16 + k];
  dt[g] = softplusf_(acc);
}

// ---------- scan pass A: chunk-local h; lane owns 8 states of 1 channel; prefetched ----------
// wave = 8 channels x 8 state-groups; NC*256 = 4096 waves
__global__ __launch_bounds__(256, 4) void k_scanA(const float* __restrict__ dt,
    const float* __restrict__ uc, const float* __restrict__ dbl,
    const float* __restrict__ A_log,
    float* __restrict__ hseg, float* __restrict__ S){
  int gw   = (blockIdx.x * 256 + threadIdx.x) >> 6;  // 0..4095
  int lane = threadIdx.x & 63;
  int dsub = lane & 7, ngrp = lane >> 3;
  int grp = gw & 255;          // channel group (8 channels)
  int c   = gw >> 8;           // chunk 0..15
  int ch  = grp * 8 + dsub;    // 0..2047
  int b = ch >> 9, d = ch & 511;
  float Aa[8];
  {
    float4 a0 = *(const float4*)(A_log + (size_t)d*64 + ngrp*8);
    float4 a1 = *(const float4*)(A_log + (size_t)d*64 + ngrp*8 + 4);
    Aa[0]=-__expf(a0.x); Aa[1]=-__expf(a0.y); Aa[2]=-__expf(a0.z); Aa[3]=-__expf(a0.w);
    Aa[4]=-__expf(a1.x); Aa[5]=-__expf(a1.y); Aa[6]=-__expf(a1.z); Aa[7]=-__expf(a1.w);
  }
  const float* dtp = dt  + (size_t)b * L_ * 512 + d;
  const float* ucp = uc  + (size_t)b * L_ * 512 + d;
  const float* Bp  = dbl + (size_t)b * L_ * 80  + 16 + ngrp*8;
  float h[8] = {};
  float Ssum = 0.f;
  int tbeg = c * CL;
  float dtc[4], uc4[4], Bc[4][8];
  float dtn[4], un4[4], Bn[4][8];
  #pragma unroll
  for (int j = 0; j < 4; j++){
    dtc[j] = dtp[(size_t)(tbeg+j) * 512];
    uc4[j] = ucp[(size_t)(tbeg+j) * 512];
    *(float4*)&Bc[j][0] = *(const float4*)(Bp + (size_t)(tbeg+j)*80);
    *(float4*)&Bc[j][4] = *(const float4*)(Bp + (size_t)(tbeg+j)*80 + 4);
  }
  for (int it = 0; it < CL/4; it++){
    int tn = tbeg + (it+1)*4;
    if (it+1 < CL/4){
      #pragma unroll
      for (int j = 0; j < 4; j++){
        dtn[j] = dtp[(size_t)(tn+j) * 512];
        un4[j] = ucp[(size_t)(tn+j) * 512];
        *(float4*)&Bn[j][0] = *(const float4*)(Bp + (size_t)(tn+j)*80);
        *(float4*)&Bn[j][4] = *(const float4*)(Bp + (size_t)(tn+j)*80 + 4);
      }
    }
    #pragma unroll
    for (int j = 0; j < 4; j++){
      float sc = dtc[j] * uc4[j];
      Ssum += dtc[j];
      #pragma unroll
      for (int i = 0; i < 8; i++)
        h[i] = __expf(dtc[j] * Aa[i]) * h[i] + sc * Bc[j][i];
    }
    #pragma unroll
    for (int j = 0; j < 4; j++){
      dtc[j] = dtn[j]; uc4[j] = un4[j];
      #pragma unroll
      for (int i = 0; i < 8; i++) Bc[j][i] = Bn[j][i];
    }
  }
  float* hp = hseg + ((size_t)(c * 2048 + ch)) * 64 + ngrp*8;
  *(float4*)hp     = make_float4(h[0],h[1],h[2],h[3]);
  *(float4*)(hp+4) = make_float4(h[4],h[5],h[6],h[7]);
  if (ngrp == 0) S[c * 2048 + ch] = Ssum;
}

// ---------- scan pass B: sequential chunk combine, IN-PLACE (hseg -> h_in) ----------
__global__ __launch_bounds__(256) void k_scanB(float* __restrict__ hseg,
    const float* __restrict__ S, const float* __restrict__ A_log){
  int ch   = (blockIdx.x * 256 + threadIdx.x) >> 6;  // 0..2047
  int lane = threadIdx.x & 63;
  int d = ch & 511;
  float A = -__expf(A_log[(size_t)d * 64 + lane]);
  float hc = 0.f;
  #pragma unroll
  for (int c = 0; c < NC; c++){
    size_t idx = ((size_t)(c * 2048 + ch)) * 64 + lane;
    float hf = hseg[idx];
    hseg[idx] = hc;                    // now holds h_in for chunk c
    float Sv = S[c * 2048 + ch];
    hc = hf + __expf(A * Sv) * hc;
  }
}

// ---------- scan pass C: rescan from h_in; batch=2, prefetched; 3-stage butterfly ----------
__global__ __launch_bounds__(256, 4) void k_scanC(const float* __restrict__ dt,
    const float* __restrict__ uc, const float* __restrict__ dbl,
    const float* __restrict__ C_SA, const float* __restrict__ A_log,
    const float* __restrict__ hin, float* __restrict__ ys){
  int gw   = (blockIdx.x * 256 + threadIdx.x) >> 6;  // 0..4095
  int lane = threadIdx.x & 63;
  int dsub = lane & 7, ngrp = lane >> 3;
  int grp = gw & 255;
  int c   = gw >> 8;
  int ch  = grp * 8 + dsub;
  int b = ch >> 9, d = ch & 511;
  float Aa[8];
  {
    float4 a0 = *(const float4*)(A_log + (size_t)d*64 + ngrp*8);
    float4 a1 = *(const float4*)(A_log + (size_t)d*64 + ngrp*8 + 4);
    Aa[0]=-__expf(a0.x); Aa[1]=-__expf(a0.y); Aa[2]=-__expf(a0.z); Aa[3]=-__expf(a0.w);
    Aa[4]=-__expf(a1.x); Aa[5]=-__expf(a1.y); Aa[6]=-__expf(a1.z); Aa[7]=-__expf(a1.w);
  }
  const float* dtp = dt   + (size_t)b * L_ * 512 + d;
  const float* ucp = uc   + (size_t)b * L_ * 512 + d;
  const float* Bp  = dbl  + (size_t)b * L_ * 80  + 16 + ngrp*8;
  const float* Cp  = C_SA + (size_t)b * L_ * 64  + ngrp*8;
  float*       yw  = ys   + (size_t)b * L_ * 512 + d;
  float h[8];
  {
    const float* hp = hin + ((size_t)(c * 2048 + ch)) * 64 + ngrp*8;
    float4 h0 = *(const float4*)hp;
    float4 h1 = *(const float4*)(hp + 4);
    h[0]=h0.x; h[1]=h0.y; h[2]=h0.z; h[3]=h0.w;
    h[4]=h1.x; h[5]=h1.y; h[6]=h1.z; h[7]=h1.w;
  }
  int tbeg = c * CL;
  float dtc[2], u2[2], Bc[2][8], Cc[2][8];
  float dtn[2], un[2], Bn[2][8], Cn[2][8];
  #pragma unroll
  for (int j = 0; j < 2; j++){
    dtc[j] = dtp[(size_t)(tbeg+j) * 512];
    u2[j]  = ucp[(size_t)(tbeg+j) * 512];
    *(float4*)&Bc[j][0] = *(const float4*)(Bp + (size_t)(tbeg+j)*80);
    *(float4*)&Bc[j][4] = *(const float4*)(Bp + (size_t)(tbeg+j)*80 + 4);
    *(float4*)&Cc[j][0] = *(const float4*)(Cp + (size_t)(tbeg+j)*64);
    *(float4*)&Cc[j][4] = *(const float4*)(Cp + (size_t)(tbeg+j)*64 + 4);
  }
  for (int it = 0; it < CL/2; it++){
    int t0 = tbeg + it*2;
    int tn = t0 + 2;
    if (it+1 < CL/2){
      #pragma unroll
      for (int j = 0; j < 2; j++){
        dtn[j] = dtp[(size_t)(tn+j) * 512];
        un[j]  = ucp[(size_t)(tn+j) * 512];
        *(float4*)&Bn[j][0] = *(const float4*)(Bp + (size_t)(tn+j)*80);
        *(float4*)&Bn[j][4] = *(const float4*)(Bp + (size_t)(tn+j)*80 + 4);
        *(float4*)&Cn[j][0] = *(const float4*)(Cp + (size_t)(tn+j)*64);
        *(float4*)&Cn[j][4] = *(const float4*)(Cp + (size_t)(tn+j)*64 + 4);
      }
    }
    float yp[2];
    #pragma unroll
    for (int j = 0; j < 2; j++){
      float sc = dtc[j] * u2[j];
      float y = 0.f;
      #pragma unroll
      for (int i = 0; i < 8; i++){
        h[i] = __expf(dtc[j] * Aa[i]) * h[i] + sc * Bc[j][i];
        y += h[i] * Cc[j][i];
      }
      yp[j] = y;
    }
    #pragma unroll
    for (int off = 8; off < 64; off <<= 1){
      #pragma unroll
      for (int j = 0; j < 2; j++)
        yp[j] += __shfl_xor(yp[j], off, 64);
    }
    if (ngrp == 0){
      yw[(size_t)(t0+0) * 512] = yp[0];
      yw[(size_t)(t0+1) * 512] = yp[1];
    }
    #pragma unroll
    for (int j = 0; j < 2; j++){
      dtc[j] = dtn[j]; u2[j] = un[j];
      #pragma unroll
      for (int i = 0; i < 8; i++){ Bc[j][i] = Bn[j][i]; Cc[j][i] = Cn[j][i]; }
    }
  }
}

// ---------- GEMM3 (gate fused): out = ((ys+uc*D)*silu(z)) . W_out^T  (4096x256x512) ----------
__global__ __launch_bounds__(256) void k_gemm3(const float* __restrict__ ys,
    const float* __restrict__ uc, const float* __restrict__ xz,
    const float* __restrict__ Dp, const float* __restrict__ Wout,
    float* __restrict__ out){
  __shared__ float As[16][64];
  __shared__ float Bs[16][64];
  int tid = threadIdx.x;
  int mBase = blockIdx.y * 64;
  int nBase = blockIdx.x * 64;
  int tx = tid & 15, ty = tid >> 4;
  int am = tid >> 2, ak = (tid & 3) << 2;
  float acc[4][4] = {};
  for (int kt = 0; kt < 512; kt += 16){
    int m = mBase + am;
    float4 yv = *(const float4*)(ys + (size_t)m*512 + kt + ak);
    float4 uv = *(const float4*)(uc + (size_t)m*512 + kt + ak);
    float4 zv = *(const float4*)(xz + (size_t)m*1024 + 512 + kt + ak);
    float4 dv = *(const float4*)(Dp + kt + ak);
    float4 bv = *(const float4*)(Wout + (size_t)(nBase+am)*512 + kt + ak);
    As[ak+0][am] = (yv.x + uv.x*dv.x) * siluf_(zv.x);
    As[ak+1][am] = (yv.y + uv.y*dv.y) * siluf_(zv.y);
    As[ak+2][am] = (yv.z + uv.z*dv.z) * siluf_(zv.z);
    As[ak+3][am] = (yv.w + uv.w*dv.w) * siluf_(zv.w);
    Bs[ak+0][am]=bv.x; Bs[ak+1][am]=bv.y; Bs[ak+2][am]=bv.z; Bs[ak+3][am]=bv.w;
    __syncthreads();
    #pragma unroll
    for (int kk=0;kk<16;kk++){
      float a[4], b[4];
      #pragma unroll
      for (int i=0;i<4;i++) a[i] = As[kk][ty*4+i];
      #pragma unroll
      for (int j=0;j<4;j++) b[j] = Bs[kk][tx*4+j];
      #pragma unroll
      for (int i=0;i<4;i++)
        #pragma unroll
        for (int j=0;j<4;j++)
          acc[i][j] += a[i]*b[j];
    }
    __syncthreads();
  }
  #pragma unroll
  for (int i=0;i<4;i++){
    float4 o = make_float4(acc[i][0],acc[i][1],acc[i][2],acc[i][3]);
    *(float4*)(out + (size_t)(mBase+ty*4+i)*256 + nBase + tx*4) = o;
  }
}

extern "C" void kernel_launch(void* const* d_in, const int* in_sizes, int n_in,
                              void* d_out, int out_size, void* d_ws, size_t ws_size,
                              hipStream_t stream) {
  const float* x      = (const float*)d_in[0];
  const float* C_SA   = (const float*)d_in[1];
  const float* gamma  = (const float*)d_in[2];
  const float* beta   = (const float*)d_in[3];
  const float* W_in   = (const float*)d_in[4];
  const float* conv_w = (const float*)d_in[5];
  const float* conv_b = (const float*)d_in[6];
  const float* W_x    = (const float*)d_in[7];
  const float* W_dt   = (const float*)d_in[8];
  const float* b_dt   = (const float*)d_in[9];
  const float* A_log  = (const float*)d_in[10];
  const float* Dw     = (const float*)d_in[11];
  const float* W_out  = (const float*)d_in[12];
  float* out = (float*)d_out;

  float* ws    = (float*)d_ws;
  float* stats = ws;                        // 16384
  float* xz    = stats + 16384;             // 4096*1024 = 4194304
  float* uc    = xz    + 4194304;           // 4096*512  = 2097152
  float* dbl   = uc    + 2097152;           // 4096*80   = 327680
  float* dtb   = dbl   + 327680;            // 2097152
  float* hseg  = dtb   + 2097152;           // NC*2048*64 = 2097152 (doubles as hin)
  float* S     = hseg  + 2097152;           // NC*2048 = 32768
  float* ysb   = S     + 32768;             // 2097152
  // total ~12.96M floats ~= 51.8 MB

  k_ln_stats<<<NTOK/4, 256, 0, stream>>>(x, stats);
  k_gemm1<<<dim3(16, 64), 256, 0, stream>>>(x, stats, gamma, beta, W_in, xz);
  k_conv <<<(NTOK*512)/256, 256, 0, stream>>>(xz, conv_w, conv_b, uc);
  k_gemm2<<<64, 256, 0, stream>>>(uc, W_x, dbl);
  k_dt   <<<(NTOK*512)/256, 256, 0, stream>>>(dbl, W_dt, b_dt, dtb);
  k_scanA<<<NC*64, 256, 0, stream>>>(dtb, uc, dbl, A_log, hseg, S);
  k_scanB<<<512, 256, 0, stream>>>(hseg, S, A_log);
  k_scanC<<<NC*64, 256, 0, stream>>>(dtb, uc, dbl, C_SA, A_log, hseg, ysb);
  k_gemm3<<<dim3(4, 64), 256, 0, stream>>>(ysb, uc, xz, Dw, W_out, out);
}

// Round 9
// 297.085 us; speedup vs baseline: 1.4800x; 1.0543x over previous
//
#include <hip/hip_runtime.h>
#include <cstdint>
#include <cstddef>

#define B_    4
#define L_    1024
#define DIM_  256
#define DI_   512
#define NTOK  (B_*L_)
#define NC    16           // scan chunks
#define CL    (L_/NC)      // chunk length = 64

__device__ __forceinline__ float siluf_(float x){ return x / (1.0f + __expf(-x)); }
__device__ __forceinline__ float softplusf_(float x){
  return (x > 15.0f) ? x : log1pf(__expf(x));
}

// ---------- LN stats: one wave per token ----------
__global__ __launch_bounds__(256) void k_ln_stats(const float* __restrict__ x,
    float* __restrict__ stats){
  int tok  = blockIdx.x * 4 + (threadIdx.x >> 6);
  int lane = threadIdx.x & 63;
  float4 v = *(const float4*)(x + (size_t)tok * DIM_ + lane * 4);
  float s  = v.x + v.y + v.z + v.w;
  float sq = v.x*v.x + v.y*v.y + v.z*v.z + v.w*v.w;
  #pragma unroll
  for (int off = 32; off; off >>= 1){
    s  += __shfl_xor(s,  off, 64);
    sq += __shfl_xor(sq, off, 64);
  }
  if (lane == 0){
    float mu = s * (1.0f / DIM_);
    stats[tok*2]   = mu;
    stats[tok*2+1] = rsqrtf(sq * (1.0f / DIM_) - mu*mu + 1e-5f);
  }
}

// ---------- GEMM1 (LN fused): xz[m,n] = LN(x)[m,:] . W_in[n,:]  (4096x1024x256) ----------
__global__ __launch_bounds__(256) void k_gemm1(const float* __restrict__ x,
    const float* __restrict__ stats, const float* __restrict__ gamma,
    const float* __restrict__ beta, const float* __restrict__ Win,
    float* __restrict__ xz){
  __shared__ float As[16][64];
  __shared__ float Bs[16][64];
  int tid = threadIdx.x;
  int mBase = blockIdx.y * 64;
  int nBase = blockIdx.x * 64;
  int tx = tid & 15, ty = tid >> 4;
  int am = tid >> 2, ak = (tid & 3) << 2;
  float mu = stats[(mBase+am)*2], rs = stats[(mBase+am)*2+1];
  float acc[4][4] = {};
  for (int kt = 0; kt < 256; kt += 16){
    float4 av = *(const float4*)(x   + (size_t)(mBase+am)*256 + kt + ak);
    float4 bv = *(const float4*)(Win + (size_t)(nBase+am)*256 + kt + ak);
    float4 gv = *(const float4*)(gamma + kt + ak);
    float4 be = *(const float4*)(beta  + kt + ak);
    As[ak+0][am] = (av.x - mu) * rs * gv.x + be.x;
    As[ak+1][am] = (av.y - mu) * rs * gv.y + be.y;
    As[ak+2][am] = (av.z - mu) * rs * gv.z + be.z;
    As[ak+3][am] = (av.w - mu) * rs * gv.w + be.w;
    Bs[ak+0][am]=bv.x; Bs[ak+1][am]=bv.y; Bs[ak+2][am]=bv.z; Bs[ak+3][am]=bv.w;
    __syncthreads();
    #pragma unroll
    for (int kk = 0; kk < 16; kk++){
      float a[4], b[4];
      #pragma unroll
      for (int i=0;i<4;i++) a[i] = As[kk][ty*4+i];
      #pragma unroll
      for (int j=0;j<4;j++) b[j] = Bs[kk][tx*4+j];
      #pragma unroll
      for (int i=0;i<4;i++)
        #pragma unroll
        for (int j=0;j<4;j++)
          acc[i][j] += a[i]*b[j];
    }
    __syncthreads();
  }
  #pragma unroll
  for (int i=0;i<4;i++){
    float4 o = make_float4(acc[i][0],acc[i][1],acc[i][2],acc[i][3]);
    *(float4*)(xz + (size_t)(mBase+ty*4+i)*1024 + nBase + tx*4) = o;
  }
}

// ---------- causal depthwise conv (w=4) + SiLU ----------
__global__ __launch_bounds__(256) void k_conv(const float* __restrict__ xz,
    const float* __restrict__ cw, const float* __restrict__ cb,
    float* __restrict__ uc){
  int g = blockIdx.x * 256 + threadIdx.x;
  int d = g & 511;
  int tok = g >> 9;
  int t = tok & (L_ - 1);
  float w0 = cw[d*4+0], w1 = cw[d*4+1], w2 = cw[d*4+2], w3 = cw[d*4+3];
  const float* up = xz + (size_t)tok * 1024 + d;
  float acc = cb[d] + w3 * up[0];
  if (t >= 1) acc += w2 * up[-1 * 1024];
  if (t >= 2) acc += w1 * up[-2 * 1024];
  if (t >= 3) acc += w0 * up[-3 * 1024];
  uc[g] = siluf_(acc);
}

// ---------- GEMM2: dbl[m,n] = uc[m,:] . W_x[n,:]  (4096x80x512), 16-row tiles ----------
__global__ __launch_bounds__(256) void k_gemm2(const float* __restrict__ uc,
    const float* __restrict__ Wx, float* __restrict__ dbl){
  __shared__ float As[16 * 516];     // 16 rows, stride 516 (bank-conflict-free)
  __shared__ float Bs[80 * 20];      // [n][kk] kk-major, stride 20
  int tid = threadIdx.x;
  int mBase = blockIdx.x * 16;
  // stage A: 16 rows x 512, float4 coalesced
  for (int idx = tid * 4; idx < 16 * 512; idx += 256 * 4){
    int r = idx >> 9, k = idx & 511;
    *(float4*)&As[r * 516 + k] = *(const float4*)(uc + (size_t)(mBase + r) * 512 + k);
  }
  int r  = tid >> 4;    // row 0..15
  int cg = tid & 15;    // col group: cols cg*5 .. cg*5+4
  float acc[5] = {};
  for (int kt = 0; kt < 512; kt += 16){
    __syncthreads();
    // stage B: 80 cols x 16 k
    for (int i = tid; i < 80 * 16; i += 256){
      int n = i >> 4, kk = i & 15;
      Bs[n * 20 + kk] = Wx[(size_t)n * 512 + kt + kk];
    }
    __syncthreads();
    #pragma unroll
    for (int k4 = 0; k4 < 16; k4 += 4){
      float4 a = *(const float4*)&As[r * 516 + kt + k4];
      float4 bb[5];
      #pragma unroll
      for (int j = 0; j < 5; j++)
        bb[j] = *(const float4*)&Bs[(cg * 5 + j) * 20 + k4];
      #pragma unroll
      for (int j = 0; j < 5; j++)
        acc[j] += a.x * bb[j].x + a.y * bb[j].y + a.z * bb[j].z + a.w * bb[j].w;
    }
  }
  #pragma unroll
  for (int j = 0; j < 5; j++)
    dbl[(size_t)(mBase + r) * 80 + cg * 5 + j] = acc[j];
}

// ---------- dt[m,d] = softplus(dbl[m,:16] . W_dt[d,:] + b_dt[d]) ----------
__global__ __launch_bounds__(256) void k_dt(const float* __restrict__ dbl,
    const float* __restrict__ Wdt, const float* __restrict__ bdt,
    float* __restrict__ dt){
  int g = blockIdx.x * 256 + threadIdx.x;
  int d = g & 511; int m = g >> 9;
  float acc = bdt[d];
  const float* r = dbl + (size_t)m * 80;
  #pragma unroll
  for (int k = 0; k < 16; k++)
    acc += r[k] * Wdt[d * 16 + k];
  dt[g] = softplusf_(acc);
}

// ---------- scan pass A: chunk-local h; lane owns 8 states of 1 channel; prefetched ----------
__global__ __launch_bounds__(256, 4) void k_scanA(const float* __restrict__ dt,
    const float* __restrict__ uc, const float* __restrict__ dbl,
    const float* __restrict__ A_log,
    float* __restrict__ hseg, float* __restrict__ S){
  int gw   = (blockIdx.x * 256 + threadIdx.x) >> 6;  // 0..4095
  int lane = threadIdx.x & 63;
  int dsub = lane & 7, ngrp = lane >> 3;
  int grp = gw & 255;          // channel group (8 channels)
  int c   = gw >> 8;           // chunk 0..15
  int ch  = grp * 8 + dsub;    // 0..2047
  int b = ch >> 9, d = ch & 511;
  float Aa[8];
  {
    float4 a0 = *(const float4*)(A_log + (size_t)d*64 + ngrp*8);
    float4 a1 = *(const float4*)(A_log + (size_t)d*64 + ngrp*8 + 4);
    Aa[0]=-__expf(a0.x); Aa[1]=-__expf(a0.y); Aa[2]=-__expf(a0.z); Aa[3]=-__expf(a0.w);
    Aa[4]=-__expf(a1.x); Aa[5]=-__expf(a1.y); Aa[6]=-__expf(a1.z); Aa[7]=-__expf(a1.w);
  }
  const float* dtp = dt  + (size_t)b * L_ * 512 + d;
  const float* ucp = uc  + (size_t)b * L_ * 512 + d;
  const float* Bp  = dbl + (size_t)b * L_ * 80  + 16 + ngrp*8;
  float h[8] = {};
  float Ssum = 0.f;
  int tbeg = c * CL;
  float dtc[4], uc4[4], Bc[4][8];
  float dtn[4], un4[4], Bn[4][8];
  #pragma unroll
  for (int j = 0; j < 4; j++){
    dtc[j] = dtp[(size_t)(tbeg+j) * 512];
    uc4[j] = ucp[(size_t)(tbeg+j) * 512];
    *(float4*)&Bc[j][0] = *(const float4*)(Bp + (size_t)(tbeg+j)*80);
    *(float4*)&Bc[j][4] = *(const float4*)(Bp + (size_t)(tbeg+j)*80 + 4);
  }
  for (int it = 0; it < CL/4; it++){
    int tn = tbeg + (it+1)*4;
    if (it+1 < CL/4){
      #pragma unroll
      for (int j = 0; j < 4; j++){
        dtn[j] = dtp[(size_t)(tn+j) * 512];
        un4[j] = ucp[(size_t)(tn+j) * 512];
        *(float4*)&Bn[j][0] = *(const float4*)(Bp + (size_t)(tn+j)*80);
        *(float4*)&Bn[j][4] = *(const float4*)(Bp + (size_t)(tn+j)*80 + 4);
      }
    }
    #pragma unroll
    for (int j = 0; j < 4; j++){
      float sc = dtc[j] * uc4[j];
      Ssum += dtc[j];
      #pragma unroll
      for (int i = 0; i < 8; i++)
        h[i] = __expf(dtc[j] * Aa[i]) * h[i] + sc * Bc[j][i];
    }
    #pragma unroll
    for (int j = 0; j < 4; j++){
      dtc[j] = dtn[j]; uc4[j] = un4[j];
      #pragma unroll
      for (int i = 0; i < 8; i++) Bc[j][i] = Bn[j][i];
    }
  }
  float* hp = hseg + ((size_t)(c * 2048 + ch)) * 64 + ngrp*8;
  *(float4*)hp     = make_float4(h[0],h[1],h[2],h[3]);
  *(float4*)(hp+4) = make_float4(h[4],h[5],h[6],h[7]);
  if (ngrp == 0) S[c * 2048 + ch] = Ssum;
}

// ---------- scan pass B: sequential chunk combine, IN-PLACE (hseg -> h_in) ----------
__global__ __launch_bounds__(256) void k_scanB(float* __restrict__ hseg,
    const float* __restrict__ S, const float* __restrict__ A_log){
  int ch   = (blockIdx.x * 256 + threadIdx.x) >> 6;  // 0..2047
  int lane = threadIdx.x & 63;
  int d = ch & 511;
  float A = -__expf(A_log[(size_t)d * 64 + lane]);
  float hc = 0.f;
  #pragma unroll
  for (int c = 0; c < NC; c++){
    size_t idx = ((size_t)(c * 2048 + ch)) * 64 + lane;
    float hf = hseg[idx];
    hseg[idx] = hc;                    // now holds h_in for chunk c
    float Sv = S[c * 2048 + ch];
    hc = hf + __expf(A * Sv) * hc;
  }
}

// ---------- scan pass C: rescan from h_in; batch=2, prefetched; 3-stage butterfly ----------
__global__ __launch_bounds__(256, 4) void k_scanC(const float* __restrict__ dt,
    const float* __restrict__ uc, const float* __restrict__ dbl,
    const float* __restrict__ C_SA, const float* __restrict__ A_log,
    const float* __restrict__ hin, float* __restrict__ ys){
  int gw   = (blockIdx.x * 256 + threadIdx.x) >> 6;  // 0..4095
  int lane = threadIdx.x & 63;
  int dsub = lane & 7, ngrp = lane >> 3;
  int grp = gw & 255;
  int c   = gw >> 8;
  int ch  = grp * 8 + dsub;
  int b = ch >> 9, d = ch & 511;
  float Aa[8];
  {
    float4 a0 = *(const float4*)(A_log + (size_t)d*64 + ngrp*8);
    float4 a1 = *(const float4*)(A_log + (size_t)d*64 + ngrp*8 + 4);
    Aa[0]=-__expf(a0.x); Aa[1]=-__expf(a0.y); Aa[2]=-__expf(a0.z); Aa[3]=-__expf(a0.w);
    Aa[4]=-__expf(a1.x); Aa[5]=-__expf(a1.y); Aa[6]=-__expf(a1.z); Aa[7]=-__expf(a1.w);
  }
  const float* dtp = dt   + (size_t)b * L_ * 512 + d;
  const float* ucp = uc   + (size_t)b * L_ * 512 + d;
  const float* Bp  = dbl  + (size_t)b * L_ * 80  + 16 + ngrp*8;
  const float* Cp  = C_SA + (size_t)b * L_ * 64  + ngrp*8;
  float*       yw  = ys   + (size_t)b * L_ * 512 + d;
  float h[8];
  {
    const float* hp = hin + ((size_t)(c * 2048 + ch)) * 64 + ngrp*8;
    float4 h0 = *(const float4*)hp;
    float4 h1 = *(const float4*)(hp + 4);
    h[0]=h0.x; h[1]=h0.y; h[2]=h0.z; h[3]=h0.w;
    h[4]=h1.x; h[5]=h1.y; h[6]=h1.z; h[7]=h1.w;
  }
  int tbeg = c * CL;
  float dtc[2], u2[2], Bc[2][8], Cc[2][8];
  float dtn[2], un[2], Bn[2][8], Cn[2][8];
  #pragma unroll
  for (int j = 0; j < 2; j++){
    dtc[j] = dtp[(size_t)(tbeg+j) * 512];
    u2[j]  = ucp[(size_t)(tbeg+j) * 512];
    *(float4*)&Bc[j][0] = *(const float4*)(Bp + (size_t)(tbeg+j)*80);
    *(float4*)&Bc[j][4] = *(const float4*)(Bp + (size_t)(tbeg+j)*80 + 4);
    *(float4*)&Cc[j][0] = *(const float4*)(Cp + (size_t)(tbeg+j)*64);
    *(float4*)&Cc[j][4] = *(const float4*)(Cp + (size_t)(tbeg+j)*64 + 4);
  }
  for (int it = 0; it < CL/2; it++){
    int t0 = tbeg + it*2;
    int tn = t0 + 2;
    if (it+1 < CL/2){
      #pragma unroll
      for (int j = 0; j < 2; j++){
        dtn[j] = dtp[(size_t)(tn+j) * 512];
        un[j]  = ucp[(size_t)(tn+j) * 512];
        *(float4*)&Bn[j][0] = *(const float4*)(Bp + (size_t)(tn+j)*80);
        *(float4*)&Bn[j][4] = *(const float4*)(Bp + (size_t)(tn+j)*80 + 4);
        *(float4*)&Cn[j][0] = *(const float4*)(Cp + (size_t)(tn+j)*64);
        *(float4*)&Cn[j][4] = *(const float4*)(Cp + (size_t)(tn+j)*64 + 4);
      }
    }
    float yp[2];
    #pragma unroll
    for (int j = 0; j < 2; j++){
      float sc = dtc[j] * u2[j];
      float y = 0.f;
      #pragma unroll
      for (int i = 0; i < 8; i++){
        h[i] = __expf(dtc[j] * Aa[i]) * h[i] + sc * Bc[j][i];
        y += h[i] * Cc[j][i];
      }
      yp[j] = y;
    }
    #pragma unroll
    for (int off = 8; off < 64; off <<= 1){
      #pragma unroll
      for (int j = 0; j < 2; j++)
        yp[j] += __shfl_xor(yp[j], off, 64);
    }
    if (ngrp == 0){
      yw[(size_t)(t0+0) * 512] = yp[0];
      yw[(size_t)(t0+1) * 512] = yp[1];
    }
    #pragma unroll
    for (int j = 0; j < 2; j++){
      dtc[j] = dtn[j]; u2[j] = un[j];
      #pragma unroll
      for (int i = 0; i < 8; i++){ Bc[j][i] = Bn[j][i]; Cc[j][i] = Cn[j][i]; }
    }
  }
}

// ---------- GEMM3 (gate fused): out = ((ys+uc*D)*silu(z)) . W_out^T  (4096x256x512) ----------
__global__ __launch_bounds__(256) void k_gemm3(const float* __restrict__ ys,
    const float* __restrict__ uc, const float* __restrict__ xz,
    const float* __restrict__ Dp, const float* __restrict__ Wout,
    float* __restrict__ out){
  __shared__ float As[16][64];
  __shared__ float Bs[16][64];
  int tid = threadIdx.x;
  int mBase = blockIdx.y * 64;
  int nBase = blockIdx.x * 64;
  int tx = tid & 15, ty = tid >> 4;
  int am = tid >> 2, ak = (tid & 3) << 2;
  float acc[4][4] = {};
  for (int kt = 0; kt < 512; kt += 16){
    int m = mBase + am;
    float4 yv = *(const float4*)(ys + (size_t)m*512 + kt + ak);
    float4 uv = *(const float4*)(uc + (size_t)m*512 + kt + ak);
    float4 zv = *(const float4*)(xz + (size_t)m*1024 + 512 + kt + ak);
    float4 dv = *(const float4*)(Dp + kt + ak);
    float4 bv = *(const float4*)(Wout + (size_t)(nBase+am)*512 + kt + ak);
    As[ak+0][am] = (yv.x + uv.x*dv.x) * siluf_(zv.x);
    As[ak+1][am] = (yv.y + uv.y*dv.y) * siluf_(zv.y);
    As[ak+2][am] = (yv.z + uv.z*dv.z) * siluf_(zv.z);
    As[ak+3][am] = (yv.w + uv.w*dv.w) * siluf_(zv.w);
    Bs[ak+0][am]=bv.x; Bs[ak+1][am]=bv.y; Bs[ak+2][am]=bv.z; Bs[ak+3][am]=bv.w;
    __syncthreads();
    #pragma unroll
    for (int kk=0;kk<16;kk++){
      float a[4], b[4];
      #pragma unroll
      for (int i=0;i<4;i++) a[i] = As[kk][ty*4+i];
      #pragma unroll
      for (int j=0;j<4;j++) b[j] = Bs[kk][tx*4+j];
      #pragma unroll
      for (int i=0;i<4;i++)
        #pragma unroll
        for (int j=0;j<4;j++)
          acc[i][j] += a[i]*b[j];
    }
    __syncthreads();
  }
  #pragma unroll
  for (int i=0;i<4;i++){
    float4 o = make_float4(acc[i][0],acc[i][1],acc[i][2],acc[i][3]);
    *(float4*)(out + (size_t)(mBase+ty*4+i)*256 + nBase + tx*4) = o;
  }
}

extern "C" void kernel_launch(void* const* d_in, const int* in_sizes, int n_in,
                              void* d_out, int out_size, void* d_ws, size_t ws_size,
                              hipStream_t stream) {
  const float* x      = (const float*)d_in[0];
  const float* C_SA   = (const float*)d_in[1];
  const float* gamma  = (const float*)d_in[2];
  const float* beta   = (const float*)d_in[3];
  const float* W_in   = (const float*)d_in[4];
  const float* conv_w = (const float*)d_in[5];
  const float* conv_b = (const float*)d_in[6];
  const float* W_x    = (const float*)d_in[7];
  const float* W_dt   = (const float*)d_in[8];
  const float* b_dt   = (const float*)d_in[9];
  const float* A_log  = (const float*)d_in[10];
  const float* Dw     = (const float*)d_in[11];
  const float* W_out  = (const float*)d_in[12];
  float* out = (float*)d_out;

  float* ws    = (float*)d_ws;
  float* stats = ws;                        // 16384
  float* xz    = stats + 16384;             // 4096*1024 = 4194304
  float* uc    = xz    + 4194304;           // 4096*512  = 2097152
  float* dbl   = uc    + 2097152;           // 4096*80   = 327680
  float* dtb   = dbl   + 327680;            // 2097152
  float* hseg  = dtb   + 2097152;           // NC*2048*64 = 2097152 (doubles as hin)
  float* S     = hseg  + 2097152;           // NC*2048 = 32768
  float* ysb   = S     + 32768;             // 2097152

  k_ln_stats<<<NTOK/4, 256, 0, stream>>>(x, stats);
  k_gemm1<<<dim3(16, 64), 256, 0, stream>>>(x, stats, gamma, beta, W_in, xz);
  k_conv <<<(NTOK*512)/256, 256, 0, stream>>>(xz, conv_w, conv_b, uc);
  k_gemm2<<<256, 256, 0, stream>>>(uc, W_x, dbl);
  k_dt   <<<(NTOK*512)/256, 256, 0, stream>>>(dbl, W_dt, b_dt, dtb);
  k_scanA<<<NC*64, 256, 0, stream>>>(dtb, uc, dbl, A_log, hseg, S);
  k_scanB<<<512, 256, 0, stream>>>(hseg, S, A_log);
  k_scanC<<<NC*64, 256, 0, stream>>>(dtb, uc, dbl, C_SA, A_log, hseg, ysb);
  k_gemm3<<<dim3(4, 64), 256, 0, stream>>>(ysb, uc, xz, Dw, W_out, out);
}